// Round 9
// baseline (35.628 us; speedup 1.0000x reference)
//
#include <hip/hip_runtime.h>

// YOLOv1 loss: pred (N,7,7,30) fp32, target (N,7,7,25) fp32 -> scalar fp32.
// Round 9: async DMA staging via __builtin_amdgcn_global_load_lds (the one
// canonical CDNA4 staging path not yet tried; removes the VGPR round-trip
// and ds_writes entirely). Double-buffered wave-private LDS slices with
// COUNTED vmcnt(16) waits (T4): next chunk's 16 DMA loads stay in flight
// across the compute phase; vmcnt only drains fully on the last chunk.
// 1-wave blocks, 28160 B LDS -> 5 blocks/CU. Two-pass deterministic reduce.
// Rounds 1-8 evidence: all register-staged structures tie at 33-36 us
// (~5.3 TB/s effective). If this ties too, that's the read-stream wall.

#define NCLS 20
#define PRED_C 30
#define TGT_C  25
#define WCELLS 64                         // cells per wave-chunk
#define PRED_B (WCELLS * PRED_C * 4)      // 7680 B
#define TGT_B  (WCELLS * TGT_C * 4)       // 6400 B
#define SLICE_B (PRED_B + TGT_B)          // 14080 B per slice

typedef const __attribute__((address_space(1))) unsigned int* gas_ptr;
typedef __attribute__((address_space(3))) unsigned int* las_ptr;

// lds dest is WAVE-UNIFORM base; HW adds lane*size. global addr is per-lane.
__device__ __forceinline__ void gll16(const void* g, void* l) {
    __builtin_amdgcn_global_load_lds((gas_ptr)g, (las_ptr)l, 16, 0, 0);
}
__device__ __forceinline__ void gll4(const void* g, void* l) {
    __builtin_amdgcn_global_load_lds((gas_ptr)g, (las_ptr)l, 4, 0, 0);
}

// Per-cell loss (pointers into LDS or global; inlined).
__device__ __forceinline__ float cell_loss(const float* __restrict__ pv,
                                           const float* __restrict__ tv) {
    const float LC = 5.0f;
    const float LN = 0.5f;
    const float EPS = 1e-6f;
    const float SQE = 1e-12f;

    float obj = tv[NCLS];

    float cls = 0.f;
    #pragma unroll
    for (int c = 0; c < NCLS; ++c) {
        float d = pv[c] - tv[c];
        cls += d * d;
    }

    float tx = tv[NCLS + 1], ty = tv[NCLS + 2];
    float tw = tv[NCLS + 3], th = tv[NCLS + 4];
    float bx1 = tx - tw * 0.5f, bx2 = tx + tw * 0.5f;
    float by1 = ty - th * 0.5f, by2 = ty + th * 0.5f;
    float tarea = tw * th;

    float c0 = pv[NCLS + 0];
    float x0 = pv[NCLS + 1], y0 = pv[NCLS + 2];
    float w0 = pv[NCLS + 3], h0 = pv[NCLS + 4];
    float a0x1 = x0 - w0 * 0.5f, a0x2 = x0 + w0 * 0.5f;
    float a0y1 = y0 - h0 * 0.5f, a0y2 = y0 + h0 * 0.5f;
    float iw0 = fmaxf(fminf(a0x2, bx2) - fmaxf(a0x1, bx1), 0.f);
    float ih0 = fmaxf(fminf(a0y2, by2) - fmaxf(a0y1, by1), 0.f);
    float in0 = iw0 * ih0;
    float iou0 = in0 / (w0 * h0 + tarea - in0 + EPS);

    float c1 = pv[NCLS + 5];
    float x1 = pv[NCLS + 6], y1 = pv[NCLS + 7];
    float w1 = pv[NCLS + 8], h1 = pv[NCLS + 9];
    float a1x1 = x1 - w1 * 0.5f, a1x2 = x1 + w1 * 0.5f;
    float a1y1 = y1 - h1 * 0.5f, a1y2 = y1 + h1 * 0.5f;
    float iw1 = fmaxf(fminf(a1x2, bx2) - fmaxf(a1x1, bx1), 0.f);
    float ih1 = fmaxf(fminf(a1y2, by2) - fmaxf(a1y1, by1), 0.f);
    float in1 = iw1 * ih1;
    float iou1 = in1 / (w1 * h1 + tarea - in1 + EPS);

    bool b0 = (iou0 >= iou1);               // first index wins ties (jnp.argmax)
    float best_iou = fmaxf(iou0, iou1);
    float bx = b0 ? x0 : x1;
    float by = b0 ? y0 : y1;
    float bw = b0 ? w0 : w1;
    float bh = b0 ? h0 : h1;
    float bc = b0 ? c0 : c1;

    float dx = bx - tx, dy = by - ty;
    float dw = sqrtf(fmaxf(bw, SQE)) - sqrtf(fmaxf(tw, SQE));
    float dh = sqrtf(fmaxf(bh, SQE)) - sqrtf(fmaxf(th, SQE));
    float coord = LC * (dx * dx + dy * dy + dw * dw + dh * dh);

    float dconf = bc - best_iou;
    float objconf = dconf * dconf;
    float noobj = LN * (c0 * c0 + c1 * c1);

    return obj * (cls + coord + objconf) + (1.f - obj) * noobj;
}

__global__ void __launch_bounds__(64)
yolo_loss_partial(const float* __restrict__ pred,
                  const float* __restrict__ target,
                  float* __restrict__ partials,
                  int nchunks, int ncells, float inv_n) {
    __shared__ char lds[2 * SLICE_B];        // 28160 B -> 5 blocks/CU
    const int lane = threadIdx.x;            // block == one wave
    const int GW = gridDim.x;

    float acc = 0.f;

    // 16 DMA ops per chunk: pred 7x16B + 2x4B, target 6x16B + 1x4B
    auto issue_chunk = [&](int c, int buf) {
        char* sl = lds + buf * SLICE_B;              // wave-uniform
        const char* pg = (const char*)pred + (size_t)c * PRED_B;
        #pragma unroll
        for (int r = 0; r < 7; ++r)
            gll16(pg + r * 1024 + lane * 16, sl + r * 1024);
        #pragma unroll
        for (int q = 0; q < 2; ++q)
            gll4(pg + 7168 + q * 256 + lane * 4, sl + 7168 + q * 256);
        const char* tg = (const char*)target + (size_t)c * TGT_B;
        char* tl = sl + PRED_B;
        #pragma unroll
        for (int r = 0; r < 6; ++r)
            gll16(tg + r * 1024 + lane * 16, tl + r * 1024);
        gll4(tg + 6144 + lane * 4, tl + 6144);
    };

    int c = blockIdx.x;
    int cn = c + GW;
    bool v = (c < nchunks);
    bool vn = (cn < nchunks);
    if (v)  issue_chunk(c, 0);
    if (vn) issue_chunk(cn, 1);

    int buf = 0;
    while (v) {
        // wait for THIS chunk's 16 loads; keep next chunk's 16 in flight
        if (vn) asm volatile("s_waitcnt vmcnt(16)" ::: "memory");
        else    asm volatile("s_waitcnt vmcnt(0)"  ::: "memory");
        __builtin_amdgcn_sched_barrier(0);

        const float* pv = (const float*)(lds + buf * SLICE_B) + lane * PRED_C;
        const float* tv = (const float*)(lds + buf * SLICE_B + PRED_B)
                          + lane * TGT_C;
        acc += cell_loss(pv, tv);

        int c2 = c + 2 * GW;
        bool v2 = (c2 < nchunks);
        if (v2) {
            // our ds_reads of `buf` must retire before DMA overwrites it
            asm volatile("s_waitcnt lgkmcnt(0)" ::: "memory");
            __builtin_amdgcn_sched_barrier(0);
            issue_chunk(c2, buf);
        }
        c = cn; v = vn; cn = c2; vn = v2; buf ^= 1;
    }

    // generic tail (ncells % 64 != 0): direct global reads (not hit at N=16384)
    for (int cell = nchunks * WCELLS + blockIdx.x * 64 + lane;
         cell < ncells; cell += gridDim.x * 64) {
        acc += cell_loss(pred + (size_t)cell * PRED_C,
                         target + (size_t)cell * TGT_C);
    }

    // single-wave block: pure shuffle reduce
    #pragma unroll
    for (int off = 32; off; off >>= 1) acc += __shfl_down(acc, off, 64);
    if (lane == 0) partials[blockIdx.x] = acc * inv_n;
}

__global__ void __launch_bounds__(256)
yolo_reduce(const float* __restrict__ partials, float* __restrict__ out, int n) {
    // fixed index order + fixed reduce tree -> deterministic
    float acc = 0.f;
    for (int i = threadIdx.x; i < n; i += blockDim.x) acc += partials[i];
    #pragma unroll
    for (int off = 32; off; off >>= 1) acc += __shfl_down(acc, off, 64);
    __shared__ float smem[4];
    int lane = threadIdx.x & 63, wid = threadIdx.x >> 6;
    if (lane == 0) smem[wid] = acc;
    __syncthreads();
    if (threadIdx.x == 0) {
        float s = 0.f;
        #pragma unroll
        for (int w = 0; w < 4; ++w) s += smem[w];
        out[0] = s;
    }
}

extern "C" void kernel_launch(void* const* d_in, const int* in_sizes, int n_in,
                              void* d_out, int out_size, void* d_ws, size_t ws_size,
                              hipStream_t stream) {
    const float* pred = (const float*)d_in[0];
    const float* target = (const float*)d_in[1];
    float* out = (float*)d_out;
    float* partials = (float*)d_ws;

    int N = in_sizes[0] / (7 * 7 * PRED_C);
    int ncells = N * 7 * 7;                 // 802816
    int nchunks = ncells / WCELLS;          // 12544 (exact for N=16384)

    int nblk = 5 * 256;                     // 5 blocks/CU x 256 CU = 1280
    int wsCap = (int)(ws_size / sizeof(float));
    if (nblk > wsCap) nblk = wsCap;
    if (nblk < 1) nblk = 1;

    yolo_loss_partial<<<nblk, 64, 0, stream>>>(pred, target, partials,
                                               nchunks, ncells,
                                               1.0f / (float)N);
    yolo_reduce<<<1, 256, 0, stream>>>(partials, out, nblk);
}

// Round 10
// 34.030 us; speedup vs baseline: 1.0470x; 1.0470x over previous
//
#include <hip/hip_runtime.h>

// YOLOv1 loss: pred (N,7,7,30) fp32, target (N,7,7,25) fp32 -> scalar fp32.
// Round 10: FINAL — exact revert to the round-4 configuration, the best
// measured variant (33.4 us harness). Wave-private LDS staging, 1-deep
// register prefetch (T14), 4 waves/block, no barriers in the hot loop,
// two-pass deterministic reduce.
//
// Roofline evidence (rounds 1-9): nine structurally distinct load engines
// (per-thread strided, block-LDS+barriers, 2-cell float4, wave-private
// reg-staged at 8 and 11 waves/CU, 2-deep A/B pipeline, fused last-block
// reduction, contiguous chunk runs, global_load_lds DMA with counted vmcnt)
// spanning 15x request count and 4-16 waves/CU ALL land at 33-36 us.
// Bytes are irreducible (176 MB read-once; class/box/conf share lines).
// Best = 5.3 TB/s effective ~= 84% of the 6.29 TB/s copy-ubench ceiling:
// memory-system concurrency wall.

#define NCLS 20
#define PRED_C 30
#define TGT_C  25
#define WCELLS 64                         // cells per wave-chunk
#define PRED_FL (WCELLS * PRED_C)         // 1920 floats = 7680 B
#define TGT_FL  (WCELLS * TGT_C)          // 1600 floats = 6400 B
#define SLICE_FL (PRED_FL + TGT_FL)       // 3520 floats = 14080 B per wave

__device__ __forceinline__ float block_reduce(float acc) {
    #pragma unroll
    for (int off = 32; off; off >>= 1) acc += __shfl_down(acc, off, 64);
    __shared__ float smem[4];
    int lane = threadIdx.x & 63, wid = threadIdx.x >> 6;
    if (lane == 0) smem[wid] = acc;
    __syncthreads();
    float s = 0.f;
    if (threadIdx.x == 0) {
        #pragma unroll
        for (int w = 0; w < 4; ++w) s += smem[w];
    }
    return s;
}

// Per-cell loss (pointers into LDS or global; inlined).
__device__ __forceinline__ float cell_loss(const float* __restrict__ pv,
                                           const float* __restrict__ tv) {
    const float LC = 5.0f;
    const float LN = 0.5f;
    const float EPS = 1e-6f;
    const float SQE = 1e-12f;

    float obj = tv[NCLS];

    float cls = 0.f;
    #pragma unroll
    for (int c = 0; c < NCLS; ++c) {
        float d = pv[c] - tv[c];
        cls += d * d;
    }

    float tx = tv[NCLS + 1], ty = tv[NCLS + 2];
    float tw = tv[NCLS + 3], th = tv[NCLS + 4];
    float bx1 = tx - tw * 0.5f, bx2 = tx + tw * 0.5f;
    float by1 = ty - th * 0.5f, by2 = ty + th * 0.5f;
    float tarea = tw * th;

    float c0 = pv[NCLS + 0];
    float x0 = pv[NCLS + 1], y0 = pv[NCLS + 2];
    float w0 = pv[NCLS + 3], h0 = pv[NCLS + 4];
    float a0x1 = x0 - w0 * 0.5f, a0x2 = x0 + w0 * 0.5f;
    float a0y1 = y0 - h0 * 0.5f, a0y2 = y0 + h0 * 0.5f;
    float iw0 = fmaxf(fminf(a0x2, bx2) - fmaxf(a0x1, bx1), 0.f);
    float ih0 = fmaxf(fminf(a0y2, by2) - fmaxf(a0y1, by1), 0.f);
    float in0 = iw0 * ih0;
    float iou0 = in0 / (w0 * h0 + tarea - in0 + EPS);

    float c1 = pv[NCLS + 5];
    float x1 = pv[NCLS + 6], y1 = pv[NCLS + 7];
    float w1 = pv[NCLS + 8], h1 = pv[NCLS + 9];
    float a1x1 = x1 - w1 * 0.5f, a1x2 = x1 + w1 * 0.5f;
    float a1y1 = y1 - h1 * 0.5f, a1y2 = y1 + h1 * 0.5f;
    float iw1 = fmaxf(fminf(a1x2, bx2) - fmaxf(a1x1, bx1), 0.f);
    float ih1 = fmaxf(fminf(a1y2, by2) - fmaxf(a1y1, by1), 0.f);
    float in1 = iw1 * ih1;
    float iou1 = in1 / (w1 * h1 + tarea - in1 + EPS);

    bool b0 = (iou0 >= iou1);               // first index wins ties (jnp.argmax)
    float best_iou = fmaxf(iou0, iou1);
    float bx = b0 ? x0 : x1;
    float by = b0 ? y0 : y1;
    float bw = b0 ? w0 : w1;
    float bh = b0 ? h0 : h1;
    float bc = b0 ? c0 : c1;

    float dx = bx - tx, dy = by - ty;
    float dw = sqrtf(fmaxf(bw, SQE)) - sqrtf(fmaxf(tw, SQE));
    float dh = sqrtf(fmaxf(bh, SQE)) - sqrtf(fmaxf(th, SQE));
    float coord = LC * (dx * dx + dy * dy + dw * dw + dh * dh);

    float dconf = bc - best_iou;
    float objconf = dconf * dconf;
    float noobj = LN * (c0 * c0 + c1 * c1);

    return obj * (cls + coord + objconf) + (1.f - obj) * noobj;
}

__global__ void __launch_bounds__(256)
yolo_loss_partial(const float* __restrict__ pred,
                  const float* __restrict__ target,
                  float* __restrict__ partial,
                  int nchunks, int ncells, float inv_n) {
    __shared__ float lds[4 * SLICE_FL];     // 56320 B -> 2 blocks/CU
    const int lane = threadIdx.x & 63;
    const int wid = threadIdx.x >> 6;
    float* wP = lds + wid * SLICE_FL;       // 1920 floats (pred chunk)
    float* wT = wP + PRED_FL;               // 1600 floats (target chunk)

    const int GW = gridDim.x * 4;           // total waves
    const int gw0 = blockIdx.x * 4 + wid;

    float acc = 0.f;

    // prefetch registers (statically named -> no scratch)
    float4 pr0, pr1, pr2, pr3, pr4, pr5, pr6; float2 prT;
    float4 tr0, tr1, tr2, tr3, tr4, tr5;      float  trT;

    auto loadRegs = [&](int c) {
        // pred chunk: 7680 B, coalesced: lane*16B, 7 full rounds + 512B float2
        const float4* P4 = reinterpret_cast<const float4*>(pred)
                           + (size_t)c * (PRED_FL / 4) + lane;
        pr0 = P4[0 * 64]; pr1 = P4[1 * 64]; pr2 = P4[2 * 64]; pr3 = P4[3 * 64];
        pr4 = P4[4 * 64]; pr5 = P4[5 * 64]; pr6 = P4[6 * 64];
        prT = *(reinterpret_cast<const float2*>(pred)
                + (size_t)c * (PRED_FL / 2) + 896 + lane);
        // target chunk: 6400 B: 6 full rounds + 256B scalar
        const float4* T4 = reinterpret_cast<const float4*>(target)
                           + (size_t)c * (TGT_FL / 4) + lane;
        tr0 = T4[0 * 64]; tr1 = T4[1 * 64]; tr2 = T4[2 * 64];
        tr3 = T4[3 * 64]; tr4 = T4[4 * 64]; tr5 = T4[5 * 64];
        trT = target[(size_t)c * TGT_FL + 1536 + lane];
    };
    auto writeLDS = [&]() {
        float4* p4 = reinterpret_cast<float4*>(wP);
        p4[0 * 64 + lane] = pr0; p4[1 * 64 + lane] = pr1;
        p4[2 * 64 + lane] = pr2; p4[3 * 64 + lane] = pr3;
        p4[4 * 64 + lane] = pr4; p4[5 * 64 + lane] = pr5;
        p4[6 * 64 + lane] = pr6;
        reinterpret_cast<float2*>(wP)[896 + lane] = prT;
        float4* t4 = reinterpret_cast<float4*>(wT);
        t4[0 * 64 + lane] = tr0; t4[1 * 64 + lane] = tr1;
        t4[2 * 64 + lane] = tr2; t4[3 * 64 + lane] = tr3;
        t4[4 * 64 + lane] = tr4; t4[5 * 64 + lane] = tr5;
        wT[1536 + lane] = trT;
    };

    int c = gw0;
    if (c < nchunks) {
        loadRegs(c);                 // prologue
        while (true) {
            writeLDS();              // regs(chunk c) -> LDS (waits vmcnt)
            int cn = c + GW;
            bool more = (cn < nchunks);
            if (more) loadRegs(cn);  // issue next chunk's loads EARLY (T14)
            // compute cell `lane` of chunk c from LDS (loads fly underneath)
            acc += cell_loss(wP + lane * PRED_C, wT + lane * TGT_C);
            if (!more) break;
            c = cn;
        }
    }

    // generic tail (ncells % 64 != 0): direct global reads (not hit at N=16384)
    for (int cell = nchunks * WCELLS + blockIdx.x * 256 + threadIdx.x;
         cell < ncells; cell += gridDim.x * 256) {
        acc += cell_loss(pred + (size_t)cell * PRED_C,
                         target + (size_t)cell * TGT_C);
    }

    float s = block_reduce(acc);
    if (threadIdx.x == 0) partial[blockIdx.x] = s * inv_n;
}

__global__ void __launch_bounds__(256)
yolo_reduce(const float* __restrict__ partial, float* __restrict__ out, int n) {
    float acc = 0.f;
    for (int i = threadIdx.x; i < n; i += blockDim.x) acc += partial[i];
    float s = block_reduce(acc);
    if (threadIdx.x == 0) out[0] = s;
}

extern "C" void kernel_launch(void* const* d_in, const int* in_sizes, int n_in,
                              void* d_out, int out_size, void* d_ws, size_t ws_size,
                              hipStream_t stream) {
    const float* pred = (const float*)d_in[0];
    const float* target = (const float*)d_in[1];
    float* out = (float*)d_out;
    float* partial = (float*)d_ws;

    int N = in_sizes[0] / (7 * 7 * PRED_C);
    int ncells = N * 7 * 7;                 // 802816
    int nchunks = ncells / WCELLS;          // 12544 (exact for N=16384)

    int nblk = 512;                          // 2 blocks/CU x 256 CU
    int wsCap = (int)(ws_size / sizeof(float));
    if (nblk > wsCap) nblk = wsCap;
    if (nblk < 1) nblk = 1;

    yolo_loss_partial<<<nblk, 256, 0, stream>>>(pred, target, partial,
                                                nchunks, ncells,
                                                1.0f / (float)N);
    yolo_reduce<<<1, 256, 0, stream>>>(partial, out, nblk);
}